// Round 15
// baseline (3148.664 us; speedup 1.0000x reference)
//
#include <hip/hip_runtime.h>
#include <stdint.h>

#define NSTEPS 256
#define NHID   256
#define NG     768     // 3*NHID
#define BPB    8       // samples per block
#define TPB    768     // 12 waves: 4 k-slices x 192 col-quads
#define NSAMP  2048

typedef float v2f __attribute__((ext_vector_type(2)));
typedef float v4f __attribute__((ext_vector_type(4)));

__device__ __forceinline__ uint32_t rotl32(uint32_t v, int r){ return (v<<r)|(v>>(32-r)); }

// JAX threefry2x32 (exact): 20 rounds, key schedule injection every 4.
__device__ __forceinline__ void tf2x32(uint32_t k0, uint32_t k1,
                                       uint32_t x0, uint32_t x1,
                                       uint32_t& o0, uint32_t& o1){
  const uint32_t ks2 = k0 ^ k1 ^ 0x1BD11BDAu;
  x0 += k0; x1 += k1;
#define TF_R(r) { x0 += x1; x1 = rotl32(x1,(r)); x1 ^= x0; }
  TF_R(13) TF_R(15) TF_R(26) TF_R(6)
  x0 += k1;  x1 += ks2 + 1u;
  TF_R(17) TF_R(29) TF_R(16) TF_R(24)
  x0 += ks2; x1 += k0 + 2u;
  TF_R(13) TF_R(15) TF_R(26) TF_R(6)
  x0 += k0;  x1 += k1 + 3u;
  TF_R(17) TF_R(29) TF_R(16) TF_R(24)
  x0 += k1;  x1 += ks2 + 4u;
  TF_R(13) TF_R(15) TF_R(26) TF_R(6)
  x0 += ks2; x1 += k0 + 5u;
#undef TF_R
  o0 = x0; o1 = x1;
}

// XLA/Eigen f32 tanh: rational approx, clamp [-9,9], |x|<4e-4 -> x
__device__ __forceinline__ float tanh_xla(float x){
  float xc = fminf(fmaxf(x, -9.0f), 9.0f);
  float x2 = xc*xc;
  float p = -2.76076847742355e-16f;
  p = fmaf(p, x2, 2.00018790482477e-13f);
  p = fmaf(p, x2, -8.60467152213735e-11f);
  p = fmaf(p, x2, 5.12229709037114e-08f);
  p = fmaf(p, x2, 1.48572235717979e-05f);
  p = fmaf(p, x2, 6.37261928875436e-04f);
  p = fmaf(p, x2, 4.89352455891786e-03f);
  p = p * xc;
  float q = 1.19825839466702e-06f;
  q = fmaf(q, x2, 1.18534705686654e-04f);
  q = fmaf(q, x2, 2.26843463243900e-03f);
  q = fmaf(q, x2, 4.89352518554385e-03f);
  float r = p / q;
  return (fabsf(x) < 0.0004f) ? x : r;
}

__device__ __forceinline__ float sigmoid_ref(float x){
  return fmaf(0.5f, tanh_xla(0.5f*x), 0.5f);
}

// v_pk_fma_f32 with src0 = pair, broadcasting one half to both result halves.
__device__ __forceinline__ void pkfma_lo(v2f h, v2f w, v2f& a){
  asm("v_pk_fma_f32 %0, %1, %2, %0 op_sel:[0,0,0] op_sel_hi:[0,1,1]"
      : "+v"(a) : "v"(h), "v"(w));
}
__device__ __forceinline__ void pkfma_hi(v2f h, v2f w, v2f& a){
  asm("v_pk_fma_f32 %0, %1, %2, %0 op_sel:[1,0,0] op_sel_hi:[1,1,1]"
      : "+v"(a) : "v"(h), "v"(w));
}

// Packed group FMA: columns {0,1} in a0, {2,3} in a1.
// Per-column k-order identical to scalar: h.x*row0, h.y*row1, h.z*row2, h.w*row3.
__device__ __forceinline__ void gfma_pk(v4f h,
                                        v4f w0, v4f w1, v4f w2, v4f w3,
                                        v2f& a0, v2f& a1){
  v2f hlo = __builtin_shufflevector(h, h, 0, 1);   // (h.x, h.y) — aligned pair
  v2f hhi = __builtin_shufflevector(h, h, 2, 3);   // (h.z, h.w)
  v2f w0l = __builtin_shufflevector(w0, w0, 0, 1), w0h = __builtin_shufflevector(w0, w0, 2, 3);
  v2f w1l = __builtin_shufflevector(w1, w1, 0, 1), w1h = __builtin_shufflevector(w1, w1, 2, 3);
  v2f w2l = __builtin_shufflevector(w2, w2, 0, 1), w2h = __builtin_shufflevector(w2, w2, 2, 3);
  v2f w3l = __builtin_shufflevector(w3, w3, 0, 1), w3h = __builtin_shufflevector(w3, w3, 2, 3);
  pkfma_lo(hlo, w0l, a0); pkfma_lo(hlo, w0h, a1);   // h.x
  pkfma_hi(hlo, w1l, a0); pkfma_hi(hlo, w1h, a1);   // h.y
  pkfma_lo(hhi, w2l, a0); pkfma_lo(hhi, w2h, a1);   // h.z
  pkfma_hi(hhi, w3l, a0); pkfma_hi(hhi, w3h, a1);   // h.w
}

#define LOADW4(W0, W1, W2, W3, rp) { \
  W0 = *(const v4f*)(rp); \
  W1 = *(const v4f*)((rp) + NG); \
  W2 = *(const v4f*)((rp) + 2*NG); \
  W3 = *(const v4f*)((rp) + 3*NG); }

__global__ __launch_bounds__(TPB, 3) void rnn_sampler(
    const float* __restrict__ Wk,    // [2][768]
    const float* __restrict__ Wr,    // [256][768]
    const float* __restrict__ Bias,  // [2][768]
    const float* __restrict__ Dk,    // [256][2]
    const float* __restrict__ Db,    // [2]
    float* __restrict__ out)         // [2048*256 samples as float][2048 logP]
{
  __shared__ float    h_lds[BPB][NHID];        // 8 KB
  __shared__ float    part[4][BPB][NG];        // 96 KB — raw per-slice partials
  __shared__ uint32_t key0[NSTEPS];            // 1 KB
  __shared__ uint32_t key1[NSTEPS];            // 1 KB
  __shared__ float    wkb_lds[2*NG];           // 6 KB — precomputed Wk[x]+bias0
  __shared__ float    bias_lds[2*NG];          // 6 KB — [0]=bias0 (x-bias), [1]=bias1
  __shared__ float    dk_lds[NHID*2];          // 2 KB
  __shared__ float    db_lds[2];
  __shared__ int      xsel[BPB];
  __shared__ float    logPs[BPB];

  const int tid  = threadIdx.x;
  const int b    = blockIdx.x;
  const int ks   = tid / 192;     // k-slice 0..3 (64 k's each), wave-uniform (3 waves/slice)
  const int cq   = tid % 192;     // column-quad: abs cols 4cq..4cq+3
  const int wid  = tid >> 6;
  const int lane = tid & 63;

  // ---- init: step keys + LDS copies of small weights ----
  if (tid < NSTEPS) {
    uint32_t o0, o1;
    tf2x32(0u, 42u, 0u, (uint32_t)tid, o0, o1);
    key0[tid] = o0; key1[tid] = o1;
  }
  for (int i = tid; i < BPB*NHID; i += TPB) (&h_lds[0][0])[i] = 0.0f;
  for (int i = tid; i < 2*NG; i += TPB) {
    bias_lds[i] = Bias[i];
    wkb_lds[i]  = Wk[i] + Bias[i % NG];   // Wk[x][n] + bias0[n], same add order as before
  }
  for (int i = tid; i < NHID*2; i += TPB) dk_lds[i] = Dk[i];
  if (tid < 2) db_lds[tid] = Db[tid];
  if (tid < BPB) { xsel[tid] = 0; logPs[tid] = 0.0f; }
  __syncthreads();

  const int k0 = ks * 64;
  const float* wp = Wr + (size_t)k0 * NG + 4*cq;

  v2f acc0[BPB], acc1[BPB];

  for (int t = 0; t <= NSTEPS; ++t) {
    // ===== Phase C for step t-1 (waves 0-7), overlapped with Phase A(t) =====
    if (t > 0 && wid < BPB) {
      const int tc = t - 1;
      const int s  = wid;
      float4 h4 = *(const float4*)&h_lds[s][lane * 4];
      float4 d0 = *(const float4*)&dk_lds[lane * 8];
      float4 d1 = *(const float4*)&dk_lds[lane * 8 + 4];
      float a0 = h4.x*d0.x + h4.y*d0.z + h4.z*d1.x + h4.w*d1.z;
      float a1 = h4.x*d0.y + h4.y*d0.w + h4.z*d1.y + h4.w*d1.w;
#pragma unroll
      for (int off = 32; off > 0; off >>= 1) {
        a0 += __shfl_down(a0, off);
        a1 += __shfl_down(a1, off);
      }
      float gv = 0.0f;
      if (lane < 2) {
        const int i = b * BPB + s;
        uint32_t o0, o1;
        tf2x32(key0[tc], key1[tc], 0u, (uint32_t)(2*i + lane), o0, o1);
        uint32_t bits = o0 ^ o1;
        const float TINY = 1.17549435e-38f;
        float u = __uint_as_float((bits >> 9) | 0x3f800000u) - 1.0f;
        u = fmaxf(TINY, u * (1.0f - TINY) + TINY);
        gv = -logf(-logf(u));
      }
      float g1 = __shfl(gv, 1);
      if (lane == 0) {
        float l0 = a0 + db_lds[0], l1 = a1 + db_lds[1];
        float m  = fmaxf(l0, l1);
        float e0 = expf(l0 - m), e1 = expf(l1 - m);
        float sum = e0 + e1;
        float p0 = e0 / sum, p1 = e1 / sum;
        float lp0 = logf(1e-10f + p0), lp1 = logf(1e-10f + p1);
        float v0 = gv + lp0, v1 = g1 + lp1;
        int st = (v1 > v0) ? 1 : 0;
        logPs[s] += st ? lp1 : lp0;
        xsel[s] = 1 + st;
        const int i = b * BPB + s;
        out[(size_t)i * NSTEPS + tc] = (float)st;
      }
    }
    if (t == NSTEPS) break;

    // ===== Phase A: h @ Wr; pk-FMA + explicit 2-deep W double-buffer =========
    // Live set: acc 32 + WA 16 + WB 16 + ptrs ~6 ≈ 78 VGPR (≤84 cap, no spill).
    // Each LOADW4 is issued one full 64-pk consume-block (~128 cyc) before use.
#pragma unroll
    for (int s = 0; s < BPB; ++s) { acc0[s] = (v2f){0.f, 0.f}; acc1[s] = (v2f){0.f, 0.f}; }

    v4f WA0, WA1, WA2, WA3, WB0, WB1, WB2, WB3;
    LOADW4(WA0, WA1, WA2, WA3, wp);            // group 0
    LOADW4(WB0, WB1, WB2, WB3, wp + 4*NG);     // group 1
    const float* rpA = wp + (size_t)8 * NG;    // group 2
    const float* rpB = wp + (size_t)12 * NG;   // group 3

#pragma unroll 1
    for (int p = 0; p < 7; ++p) {
      const int g = 2 * p;
#pragma unroll
      for (int s = 0; s < BPB; ++s) {          // consume even group g
        v4f h4 = *(const v4f*)&h_lds[s][k0 + 4*g];
        gfma_pk(h4, WA0, WA1, WA2, WA3, acc0[s], acc1[s]);
      }
      LOADW4(WA0, WA1, WA2, WA3, rpA);         // prefetch group g+2
      rpA += 8 * NG;
#pragma unroll
      for (int s = 0; s < BPB; ++s) {          // consume odd group g+1
        v4f h4 = *(const v4f*)&h_lds[s][k0 + 4*g + 4];
        gfma_pk(h4, WB0, WB1, WB2, WB3, acc0[s], acc1[s]);
      }
      LOADW4(WB0, WB1, WB2, WB3, rpB);         // prefetch group g+3
      rpB += 8 * NG;
    }
    // peeled tail: groups 14, 15 — no further loads, W regs die here
#pragma unroll
    for (int s = 0; s < BPB; ++s) {
      v4f h4 = *(const v4f*)&h_lds[s][k0 + 4*14];
      gfma_pk(h4, WA0, WA1, WA2, WA3, acc0[s], acc1[s]);
    }
#pragma unroll
    for (int s = 0; s < BPB; ++s) {
      v4f h4 = *(const v4f*)&h_lds[s][k0 + 4*15];
      gfma_pk(h4, WB0, WB1, WB2, WB3, acc0[s], acc1[s]);
    }

    // raw per-slice write — single barrier, no read-modify-write
#pragma unroll
    for (int s = 0; s < BPB; ++s) {
      *(v2f*)&part[ks][s][4*cq]     = acc0[s];
      *(v2f*)&part[ks][s][4*cq + 2] = acc1[s];
    }
    __syncthreads();

    // ===== Phase B: gates -> h_new, float4 per thread, threads 256-767 =======
    {
      const int bt = tid - 256;
      if ((unsigned)bt < 512u) {
        const int s = bt >> 6;            // wave-uniform
        const int n = (bt & 63) << 2;     // col base, lane-stride 16B
        float4 pz0 = *(const float4*)&part[0][s][n];
        float4 pz2 = *(const float4*)&part[2][s][n];
        float4 pz1 = *(const float4*)&part[1][s][n];
        float4 pz3 = *(const float4*)&part[3][s][n];
        float4 pr0 = *(const float4*)&part[0][s][n+256];
        float4 pr2 = *(const float4*)&part[2][s][n+256];
        float4 pr1 = *(const float4*)&part[1][s][n+256];
        float4 pr3 = *(const float4*)&part[3][s][n+256];
        float4 pn0 = *(const float4*)&part[0][s][n+512];
        float4 pn2 = *(const float4*)&part[2][s][n+512];
        float4 pn1 = *(const float4*)&part[1][s][n+512];
        float4 pn3 = *(const float4*)&part[3][s][n+512];
        float4 bhz = *(const float4*)&bias_lds[NG + n];
        float4 bhr = *(const float4*)&bias_lds[NG + n + 256];
        float4 bhn = *(const float4*)&bias_lds[NG + n + 512];
        const int xs = xsel[s];            // wave-uniform select, no adds
        const float* gxp = (xs == 0) ? bias_lds : &wkb_lds[(xs - 1) * NG];
        float4 gxz = *(const float4*)&gxp[n];
        float4 gxr = *(const float4*)&gxp[n + 256];
        float4 gxh = *(const float4*)&gxp[n + 512];
        float4 ho = *(const float4*)&h_lds[s][n];
        float4 hnew;
#define GCOMP(c) { \
        float ghz = ((pz0.c + pz2.c) + (pz1.c + pz3.c)) + bhz.c; \
        float ghr = ((pr0.c + pr2.c) + (pr1.c + pr3.c)) + bhr.c; \
        float ghn = ((pn0.c + pn2.c) + (pn1.c + pn3.c)) + bhn.c; \
        float zg = sigmoid_ref(gxz.c + ghz); \
        float rg = sigmoid_ref(gxr.c + ghr); \
        float hh = tanh_xla(gxh.c + rg * ghn); \
        hnew.c = zg * ho.c + (1.0f - zg) * hh; }
        GCOMP(x) GCOMP(y) GCOMP(z) GCOMP(w)
#undef GCOMP
        *(float4*)&h_lds[s][n] = hnew;
      }
    }
    __syncthreads();
  }

  __syncthreads();   // logPs[s] written by wave s lane 0 during final Phase C

  // ---- epilogue: logP as float32 ----
  if (tid < BPB) {
    const int i = b * BPB + tid;
    out[(size_t)NSAMP * NSTEPS + i] = logPs[tid];
  }
}

extern "C" void kernel_launch(void* const* d_in, const int* in_sizes, int n_in,
                              void* d_out, int out_size, void* d_ws, size_t ws_size,
                              hipStream_t stream) {
  const float* Wk = (const float*)d_in[0];  // gru_kernel     [2,768]
  const float* Wr = (const float*)d_in[1];  // gru_rec_kernel [256,768]
  const float* B  = (const float*)d_in[2];  // gru_bias       [2,768]
  const float* Dk = (const float*)d_in[3];  // dense_kernel   [256,2]
  const float* Db = (const float*)d_in[4];  // dense_bias     [2]
  float* out = (float*)d_out;
  rnn_sampler<<<dim3(NSAMP / BPB), dim3(TPB), 0, stream>>>(Wk, Wr, B, Dk, Db, out);
}

// Round 16
// 3003.070 us; speedup vs baseline: 1.0485x; 1.0485x over previous
//
#include <hip/hip_runtime.h>
#include <stdint.h>

#define NSTEPS 256
#define NHID   256
#define NG     768     // 3*NHID
#define BPB    8       // samples per block
#define TPB    768     // 12 waves: 4 k-slices x 192 col-quads
#define NSAMP  2048

typedef float v2f __attribute__((ext_vector_type(2)));
typedef float v4f __attribute__((ext_vector_type(4)));

__device__ __forceinline__ uint32_t rotl32(uint32_t v, int r){ return (v<<r)|(v>>(32-r)); }

// JAX threefry2x32 (exact): 20 rounds, key schedule injection every 4.
__device__ __forceinline__ void tf2x32(uint32_t k0, uint32_t k1,
                                       uint32_t x0, uint32_t x1,
                                       uint32_t& o0, uint32_t& o1){
  const uint32_t ks2 = k0 ^ k1 ^ 0x1BD11BDAu;
  x0 += k0; x1 += k1;
#define TF_R(r) { x0 += x1; x1 = rotl32(x1,(r)); x1 ^= x0; }
  TF_R(13) TF_R(15) TF_R(26) TF_R(6)
  x0 += k1;  x1 += ks2 + 1u;
  TF_R(17) TF_R(29) TF_R(16) TF_R(24)
  x0 += ks2; x1 += k0 + 2u;
  TF_R(13) TF_R(15) TF_R(26) TF_R(6)
  x0 += k0;  x1 += k1 + 3u;
  TF_R(17) TF_R(29) TF_R(16) TF_R(24)
  x0 += k1;  x1 += ks2 + 4u;
  TF_R(13) TF_R(15) TF_R(26) TF_R(6)
  x0 += ks2; x1 += k0 + 5u;
#undef TF_R
  o0 = x0; o1 = x1;
}

// XLA/Eigen f32 tanh: rational approx, clamp [-9,9], |x|<4e-4 -> x
__device__ __forceinline__ float tanh_xla(float x){
  float xc = fminf(fmaxf(x, -9.0f), 9.0f);
  float x2 = xc*xc;
  float p = -2.76076847742355e-16f;
  p = fmaf(p, x2, 2.00018790482477e-13f);
  p = fmaf(p, x2, -8.60467152213735e-11f);
  p = fmaf(p, x2, 5.12229709037114e-08f);
  p = fmaf(p, x2, 1.48572235717979e-05f);
  p = fmaf(p, x2, 6.37261928875436e-04f);
  p = fmaf(p, x2, 4.89352455891786e-03f);
  p = p * xc;
  float q = 1.19825839466702e-06f;
  q = fmaf(q, x2, 1.18534705686654e-04f);
  q = fmaf(q, x2, 2.26843463243900e-03f);
  q = fmaf(q, x2, 4.89352518554385e-03f);
  float r = p / q;
  return (fabsf(x) < 0.0004f) ? x : r;
}

__device__ __forceinline__ float sigmoid_ref(float x){
  return fmaf(0.5f, tanh_xla(0.5f*x), 0.5f);
}

// v_pk_fma_f32 with src0 = pair, broadcasting one half to both result halves.
__device__ __forceinline__ void pkfma_lo(v2f h, v2f w, v2f& a){
  asm("v_pk_fma_f32 %0, %1, %2, %0 op_sel:[0,0,0] op_sel_hi:[0,1,1]"
      : "+v"(a) : "v"(h), "v"(w));
}
__device__ __forceinline__ void pkfma_hi(v2f h, v2f w, v2f& a){
  asm("v_pk_fma_f32 %0, %1, %2, %0 op_sel:[1,0,0] op_sel_hi:[1,1,1]"
      : "+v"(a) : "v"(h), "v"(w));
}

// Packed group FMA: columns {0,1} in a0, {2,3} in a1.
// Per-column k-order identical to scalar: h.x*row0, h.y*row1, h.z*row2, h.w*row3.
__device__ __forceinline__ void gfma_pk(v4f h,
                                        v4f w0, v4f w1, v4f w2, v4f w3,
                                        v2f& a0, v2f& a1){
  v2f hlo = __builtin_shufflevector(h, h, 0, 1);   // (h.x, h.y) — aligned pair
  v2f hhi = __builtin_shufflevector(h, h, 2, 3);   // (h.z, h.w)
  v2f w0l = __builtin_shufflevector(w0, w0, 0, 1), w0h = __builtin_shufflevector(w0, w0, 2, 3);
  v2f w1l = __builtin_shufflevector(w1, w1, 0, 1), w1h = __builtin_shufflevector(w1, w1, 2, 3);
  v2f w2l = __builtin_shufflevector(w2, w2, 0, 1), w2h = __builtin_shufflevector(w2, w2, 2, 3);
  v2f w3l = __builtin_shufflevector(w3, w3, 0, 1), w3h = __builtin_shufflevector(w3, w3, 2, 3);
  pkfma_lo(hlo, w0l, a0); pkfma_lo(hlo, w0h, a1);   // h.x
  pkfma_hi(hlo, w1l, a0); pkfma_hi(hlo, w1h, a1);   // h.y
  pkfma_lo(hhi, w2l, a0); pkfma_lo(hhi, w2h, a1);   // h.z
  pkfma_hi(hhi, w3l, a0); pkfma_hi(hhi, w3h, a1);   // h.w
}

__global__ __launch_bounds__(TPB, 3) void rnn_sampler(
    const float* __restrict__ Wk,    // [2][768]
    const float* __restrict__ Wr,    // [256][768]
    const float* __restrict__ Bias,  // [2][768]
    const float* __restrict__ Dk,    // [256][2]
    const float* __restrict__ Db,    // [2]
    float* __restrict__ out)         // [2048*256 samples as float][2048 logP]
{
  __shared__ float    h_lds[BPB][NHID];        // 8 KB
  __shared__ float    part[4][BPB][NG];        // 96 KB — raw per-slice partials
  __shared__ uint32_t key0[NSTEPS];            // 1 KB
  __shared__ uint32_t key1[NSTEPS];            // 1 KB
  __shared__ float    wkb_lds[2*NG];           // 6 KB — precomputed Wk[x]+bias0
  __shared__ float    bias_lds[2*NG];          // 6 KB
  __shared__ float    dk_lds[NHID*2];          // 2 KB
  __shared__ float    db_lds[2];
  __shared__ int      xsel[BPB];
  __shared__ float    logPs[BPB];

  const int tid  = threadIdx.x;
  const int b    = blockIdx.x;
  const int ks   = tid / 192;     // k-slice 0..3 (64 k's each), wave-uniform (3 waves/slice)
  const int cq   = tid % 192;     // column-quad: abs cols 4cq..4cq+3
  const int wid  = tid >> 6;
  const int lane = tid & 63;

  // ---- init: step keys + LDS copies of small weights ----
  if (tid < NSTEPS) {
    uint32_t o0, o1;
    tf2x32(0u, 42u, 0u, (uint32_t)tid, o0, o1);
    key0[tid] = o0; key1[tid] = o1;
  }
  for (int i = tid; i < BPB*NHID; i += TPB) (&h_lds[0][0])[i] = 0.0f;
  for (int i = tid; i < 2*NG; i += TPB) {
    bias_lds[i] = Bias[i];
    wkb_lds[i]  = Wk[i] + Bias[i % NG];   // Wk[x][n] + bias0[n], same add order as before
  }
  for (int i = tid; i < NHID*2; i += TPB) dk_lds[i] = Dk[i];
  if (tid < 2) db_lds[tid] = Db[tid];
  if (tid < BPB) { xsel[tid] = 0; logPs[tid] = 0.0f; }
  __syncthreads();

  const int k0 = ks * 64;
  const float* wp = Wr + (size_t)k0 * NG + 4*cq;

  v2f acc0[BPB], acc1[BPB];

  for (int t = 0; t <= NSTEPS; ++t) {
    // ===== Phase C for step t-1 (waves 0-7), overlapped with Phase A(t) =====
    if (t > 0 && wid < BPB) {
      const int tc = t - 1;
      const int s  = wid;
      float4 h4 = *(const float4*)&h_lds[s][lane * 4];
      float4 d0 = *(const float4*)&dk_lds[lane * 8];
      float4 d1 = *(const float4*)&dk_lds[lane * 8 + 4];
      float a0 = h4.x*d0.x + h4.y*d0.z + h4.z*d1.x + h4.w*d1.z;
      float a1 = h4.x*d0.y + h4.y*d0.w + h4.z*d1.y + h4.w*d1.w;
#pragma unroll
      for (int off = 32; off > 0; off >>= 1) {
        a0 += __shfl_down(a0, off);
        a1 += __shfl_down(a1, off);
      }
      float gv = 0.0f;
      if (lane < 2) {
        const int i = b * BPB + s;
        uint32_t o0, o1;
        tf2x32(key0[tc], key1[tc], 0u, (uint32_t)(2*i + lane), o0, o1);
        uint32_t bits = o0 ^ o1;
        const float TINY = 1.17549435e-38f;
        float u = __uint_as_float((bits >> 9) | 0x3f800000u) - 1.0f;
        u = fmaxf(TINY, u * (1.0f - TINY) + TINY);
        gv = -logf(-logf(u));
      }
      float g1 = __shfl(gv, 1);
      if (lane == 0) {
        float l0 = a0 + db_lds[0], l1 = a1 + db_lds[1];
        float m  = fmaxf(l0, l1);
        float e0 = expf(l0 - m), e1 = expf(l1 - m);
        float sum = e0 + e1;
        float p0 = e0 / sum, p1 = e1 / sum;
        float lp0 = logf(1e-10f + p0), lp1 = logf(1e-10f + p1);
        float v0 = gv + lp0, v1 = g1 + lp1;
        int st = (v1 > v0) ? 1 : 0;
        logPs[s] += st ? lp1 : lp0;
        xsel[s] = 1 + st;
        const int i = b * BPB + s;
        out[(size_t)i * NSTEPS + tc] = (float)st;
      }
    }
    if (t == NSTEPS) break;

    // ===== Phase A: h @ Wr; pk-FMA, single-buffered W, unroll-2 (r14 shape) ==
#pragma unroll
    for (int s = 0; s < BPB; ++s) { acc0[s] = (v2f){0.f, 0.f}; acc1[s] = (v2f){0.f, 0.f}; }

#pragma unroll 2
    for (int g = 0; g < 16; ++g) {
      const float* rp = wp + (size_t)(4*g) * NG;
      v4f w0 = *(const v4f*)(rp);
      v4f w1 = *(const v4f*)(rp + NG);
      v4f w2 = *(const v4f*)(rp + 2*NG);
      v4f w3 = *(const v4f*)(rp + 3*NG);
#pragma unroll
      for (int s = 0; s < BPB; ++s) {
        v4f h4 = *(const v4f*)&h_lds[s][k0 + 4*g];
        gfma_pk(h4, w0, w1, w2, w3, acc0[s], acc1[s]);
      }
    }

    // raw per-slice write — single barrier, no read-modify-write
#pragma unroll
    for (int s = 0; s < BPB; ++s) {
      *(v2f*)&part[ks][s][4*cq]     = acc0[s];
      *(v2f*)&part[ks][s][4*cq + 2] = acc1[s];
    }
    __syncthreads();

    // ===== Phase B: gates -> h_new, float4 per thread, threads 256-767 =======
    {
      const int bt = tid - 256;
      if ((unsigned)bt < 512u) {
        const int s = bt >> 6;            // wave-uniform
        const int n = (bt & 63) << 2;     // col base, lane-stride 16B
        float4 pz0 = *(const float4*)&part[0][s][n];
        float4 pz2 = *(const float4*)&part[2][s][n];
        float4 pz1 = *(const float4*)&part[1][s][n];
        float4 pz3 = *(const float4*)&part[3][s][n];
        float4 pr0 = *(const float4*)&part[0][s][n+256];
        float4 pr2 = *(const float4*)&part[2][s][n+256];
        float4 pr1 = *(const float4*)&part[1][s][n+256];
        float4 pr3 = *(const float4*)&part[3][s][n+256];
        float4 pn0 = *(const float4*)&part[0][s][n+512];
        float4 pn2 = *(const float4*)&part[2][s][n+512];
        float4 pn1 = *(const float4*)&part[1][s][n+512];
        float4 pn3 = *(const float4*)&part[3][s][n+512];
        float4 bhz = *(const float4*)&bias_lds[NG + n];
        float4 bhr = *(const float4*)&bias_lds[NG + n + 256];
        float4 bhn = *(const float4*)&bias_lds[NG + n + 512];
        const int xs = xsel[s];            // wave-uniform select, no adds
        const float* gxp = (xs == 0) ? bias_lds : &wkb_lds[(xs - 1) * NG];
        float4 gxz = *(const float4*)&gxp[n];
        float4 gxr = *(const float4*)&gxp[n + 256];
        float4 gxh = *(const float4*)&gxp[n + 512];
        float4 ho = *(const float4*)&h_lds[s][n];
        float4 hnew;
#define GCOMP(c) { \
        float ghz = ((pz0.c + pz2.c) + (pz1.c + pz3.c)) + bhz.c; \
        float ghr = ((pr0.c + pr2.c) + (pr1.c + pr3.c)) + bhr.c; \
        float ghn = ((pn0.c + pn2.c) + (pn1.c + pn3.c)) + bhn.c; \
        float zg = sigmoid_ref(gxz.c + ghz); \
        float rg = sigmoid_ref(gxr.c + ghr); \
        float hh = tanh_xla(gxh.c + rg * ghn); \
        hnew.c = zg * ho.c + (1.0f - zg) * hh; }
        GCOMP(x) GCOMP(y) GCOMP(z) GCOMP(w)
#undef GCOMP
        *(float4*)&h_lds[s][n] = hnew;
      }
    }
    __syncthreads();
  }

  __syncthreads();   // logPs[s] written by wave s lane 0 during final Phase C

  // ---- epilogue: logP as float32 ----
  if (tid < BPB) {
    const int i = b * BPB + tid;
    out[(size_t)NSAMP * NSTEPS + i] = logPs[tid];
  }
}

extern "C" void kernel_launch(void* const* d_in, const int* in_sizes, int n_in,
                              void* d_out, int out_size, void* d_ws, size_t ws_size,
                              hipStream_t stream) {
  const float* Wk = (const float*)d_in[0];  // gru_kernel     [2,768]
  const float* Wr = (const float*)d_in[1];  // gru_rec_kernel [256,768]
  const float* B  = (const float*)d_in[2];  // gru_bias       [2,768]
  const float* Dk = (const float*)d_in[3];  // dense_kernel   [256,2]
  const float* Db = (const float*)d_in[4];  // dense_bias     [2]
  float* out = (float*)d_out;
  rnn_sampler<<<dim3(NSAMP / BPB), dim3(TPB), 0, stream>>>(Wk, Wr, B, Dk, Db, out);
}